// Round 17
// baseline (1191.497 us; speedup 1.0000x reference)
//
#include <hip/hip_runtime.h>
#include <hip/hip_cooperative_groups.h>

namespace cg = cooperative_groups;

#define NN 50000
#define HH 8
#define ALPHA 0.2f
#define NPAD 50048   // NN rounded up to 128

typedef short short8 __attribute__((ext_vector_type(8)));
typedef float f32x4 __attribute__((ext_vector_type(4)));

__device__ __forceinline__ float elu_f(float x) {
  return x > 0.f ? x : __expf(x) - 1.f;
}

__device__ __forceinline__ unsigned short f2bf(float f) {
  unsigned int u = __float_as_uint(f);
  unsigned int r = (u + 0x7fffu + ((u >> 16) & 1u)) >> 16;
  return (unsigned short)r;
}

// ================= single cooperative mega-kernel =================
// stages: S0 prep -> S1 hist -> S2 scan -> S3 scatter+gemm1 -> S4 agg1
//         -> S5 gemm2 -> S6 agg2+classifier, grid.sync() between.
__global__ __launch_bounds__(256, 4) void mega_kernel(
    const float* __restrict__ x, const int* __restrict__ esrc, const int* __restrict__ edst,
    const float* __restrict__ W, const float* __restrict__ Aatt,
    const float* __restrict__ Wo, const float* __restrict__ ao,
    const float* __restrict__ mw, const float* __restrict__ mb, float* __restrict__ out,
    unsigned short* __restrict__ xb, unsigned short* __restrict__ Wtc,
    unsigned short* __restrict__ Wot, unsigned short* __restrict__ h1b,
    float* __restrict__ ss1, float* __restrict__ sd1,
    unsigned short* __restrict__ xc, unsigned short* __restrict__ h2b,
    float* __restrict__ ss2, float* __restrict__ sd2,
    int* __restrict__ row_ptr, int* __restrict__ nxt, int* __restrict__ cnt,
    int* __restrict__ colv, int E) {
  __shared__ __align__(16) char smem[20480];
  cg::grid_group grid = cg::this_grid();
  const int tid = threadIdx.x;
  const int gsz = gridDim.x;

  // ---------------- S0: prep (xb/Wtc/Wot bf16 conversions + cnt zero) ----------------
  {
    const int n4x = NPAD * 64;
    const int total = n4x + 512 * 256 + 64 * 512 + NN;
    for (int t = blockIdx.x * 256 + tid; t < total; t += gsz * 256) {
      if (t < n4x) {
        int row = t >> 6;
        ushort4 o;
        if (row < NN) {
          float4 v = ((const float4*)x)[t];
          o.x = f2bf(v.x); o.y = f2bf(v.y); o.z = f2bf(v.z); o.w = f2bf(v.w);
        } else {
          o.x = o.y = o.z = o.w = 0;
        }
        ((ushort4*)xb)[t] = o;
      } else {
        int t1 = t - n4x;
        if (t1 < 512 * 256) {
          int c = t1 >> 8, k = t1 & 255;
          int h = c >> 6, cc = c & 63;
          Wtc[t1] = f2bf(W[((size_t)h * 256 + k) * 64 + cc]);
        } else {
          int t2 = t1 - 512 * 256;
          if (t2 < 64 * 512) {
            int c = t2 >> 9, k = t2 & 511;
            Wot[t2] = f2bf(Wo[(size_t)k * 64 + c]);
          } else {
            int t3 = t2 - 64 * 512;
            if (t3 < NN) cnt[t3] = 0;
          }
        }
      }
    }
  }
  __threadfence();
  grid.sync();

  // ---------------- S1: degree histogram ----------------
  for (int e = blockIdx.x * 256 + tid; e < E; e += gsz * 256)
    atomicAdd(&cnt[esrc[e]], 1);
  __threadfence();
  grid.sync();

  // ---------------- S2: exclusive scan -> row_ptr, nxt ----------------
  {
    int* sh = (int*)smem;                   // sh[0..255] partials, sh[256..259] base wave-sums
    const int nch = (NN + 1023) >> 10;      // 49
    for (int chunk = blockIdx.x; chunk < nch; chunk += gsz) {
      int lim = chunk << 10;
      int s = 0;
      for (int q = tid; q < lim; q += 256) s += cnt[q];
#pragma unroll
      for (int off = 1; off < 64; off <<= 1) s += __shfl_xor(s, off, 64);
      int i0 = lim + (tid << 2);
      int v0 = (i0     < NN) ? cnt[i0]     : 0;
      int v1 = (i0 + 1 < NN) ? cnt[i0 + 1] : 0;
      int v2 = (i0 + 2 < NN) ? cnt[i0 + 2] : 0;
      int v3 = (i0 + 3 < NN) ? cnt[i0 + 3] : 0;
      int tsum = v0 + v1 + v2 + v3;
      __syncthreads();
      if ((tid & 63) == 0) sh[256 + (tid >> 6)] = s;
      sh[tid] = tsum;
      __syncthreads();
      for (int off = 1; off < 256; off <<= 1) {
        int tv = (tid >= off) ? sh[tid - off] : 0;
        __syncthreads();
        sh[tid] += tv;
        __syncthreads();
      }
      int base = sh[256] + sh[257] + sh[258] + sh[259];
      int r = base + sh[tid] - tsum;        // exclusive prefix for this thread's 4
      if (i0     < NN) { row_ptr[i0]     = r; nxt[i0]     = r; } r += v0;
      if (i0 + 1 < NN) { row_ptr[i0 + 1] = r; nxt[i0 + 1] = r; } r += v1;
      if (i0 + 2 < NN) { row_ptr[i0 + 2] = r; nxt[i0 + 2] = r; } r += v2;
      if (i0 + 3 < NN) { row_ptr[i0 + 3] = r; nxt[i0 + 3] = r; }
      __syncthreads();
    }
    if (blockIdx.x == 0 && tid == 0) row_ptr[NN] = E;
  }
  __threadfence();
  grid.sync();

  // ---------------- S3: scatter + layer-1 GEMM ----------------
  {
    const int eb = (E + 255) >> 8;
    const int gtiles = (NPAD / 128) * 4;
    typedef unsigned short (*Arr40)[40];
    Arr40 As = (Arr40)smem;
    Arr40 Bs = (Arr40)(smem + 10240);
    const int w = tid >> 6, L = tid & 63;
    const int quad = L >> 4, l16 = L & 15;
    const int wr = w >> 1, wc = w & 1;
    const int sr0 = tid >> 2;
    const int sk0 = (tid & 3) << 3;

    for (int vb = blockIdx.x; vb < eb + gtiles; vb += gsz) {
      if (vb < eb) {
        int e = vb * 256 + tid;
        if (e < E) {
          int p = atomicAdd(&nxt[esrc[e]], 1);
          colv[p] = edst[e];
        }
        continue;
      }
      int tile = vb - eb;
      int m0 = (tile >> 2) * 128;
      int c0 = (tile & 3) * 128;
      int y = (tile & 3) * 2 + wc;

      f32x4 acc[4][4];
#pragma unroll
      for (int mt = 0; mt < 4; ++mt)
#pragma unroll
        for (int nt = 0; nt < 4; ++nt) acc[mt][nt] = (f32x4)(0.f);

      for (int k0 = 0; k0 < 256; k0 += 32) {
        __syncthreads();
        *(uint4*)&As[sr0][sk0]      = *(const uint4*)(xb + (size_t)(m0 + sr0) * 256 + k0 + sk0);
        *(uint4*)&As[sr0 + 64][sk0] = *(const uint4*)(xb + (size_t)(m0 + sr0 + 64) * 256 + k0 + sk0);
        *(uint4*)&Bs[sr0][sk0]      = *(const uint4*)(Wtc + (size_t)(c0 + sr0) * 256 + k0 + sk0);
        *(uint4*)&Bs[sr0 + 64][sk0] = *(const uint4*)(Wtc + (size_t)(c0 + sr0 + 64) * 256 + k0 + sk0);
        __syncthreads();

        short8 af[4], bf[4];
#pragma unroll
        for (int mt = 0; mt < 4; ++mt)
          af[mt] = *(const short8*)&As[wr * 64 + mt * 16 + l16][quad * 8];
#pragma unroll
        for (int nt = 0; nt < 4; ++nt)
          bf[nt] = *(const short8*)&Bs[wc * 64 + nt * 16 + l16][quad * 8];
#pragma unroll
        for (int mt = 0; mt < 4; ++mt)
#pragma unroll
          for (int nt = 0; nt < 4; ++nt)
            acc[mt][nt] = __builtin_amdgcn_mfma_f32_16x16x32_bf16(af[mt], bf[nt], acc[mt][nt], 0, 0, 0);
      }

      float as[4], ad[4];
#pragma unroll
      for (int nt = 0; nt < 4; ++nt) {
        as[nt] = Aatt[y * 128 + l16 + 16 * nt];
        ad[nt] = Aatt[y * 128 + 64 + l16 + 16 * nt];
      }
#pragma unroll
      for (int mt = 0; mt < 4; ++mt) {
#pragma unroll
        for (int reg = 0; reg < 4; ++reg) {
          int row = m0 + wr * 64 + mt * 16 + quad * 4 + reg;
          float p = 0.f, q = 0.f;
#pragma unroll
          for (int nt = 0; nt < 4; ++nt) {
            p += acc[mt][nt][reg] * as[nt];
            q += acc[mt][nt][reg] * ad[nt];
          }
#pragma unroll
          for (int off = 1; off < 16; off <<= 1) {
            p += __shfl_xor(p, off, 64);
            q += __shfl_xor(q, off, 64);
          }
          if (l16 == 0 && row < NN) {
            ss1[(size_t)row * 8 + y] = p;
            sd1[(size_t)row * 8 + y] = q;
          }
          if (row < NN) {
#pragma unroll
            for (int nt = 0; nt < 4; ++nt)
              h1b[(size_t)row * 512 + y * 64 + l16 + 16 * nt] = f2bf(acc[mt][nt][reg]);
          }
        }
      }
    }
  }
  __threadfence();
  grid.sync();

  // ---------------- S4: layer-1 aggregation ----------------
  {
    const int nbb = (NN + 3) / 4;  // 12500
    const int wid = tid >> 6, L = tid & 63;
    const int hq = L >> 4;
    const int el = L & 15;
    for (int vb = blockIdx.x; vb < 2 * nbb; vb += gsz) {
      int r8 = vb & 7;
      int p = r8 >> 2;
      int nb = ((vb >> 3) << 2) | (r8 & 3);
      int n = nb * 4 + wid;
      if (n >= NN) continue;
      int h = p * 4 + hq;
      float ssn = ss1[n * 8 + h];
      int k0 = row_ptr[n], deg = row_ptr[n + 1] - k0;
      float acc[4] = {0.f, 0.f, 0.f, 0.f};
      float rs = 0.f;
      const char* tb = (const char*)h1b + p * 512;

      for (int c0 = 0; c0 < deg; c0 += 64) {
        int j = c0 + L;
        int d_l = (j < deg) ? colv[k0 + j] : 0;
        int m = min(64, deg - c0);
        for (int g = 0; g < m; g += 16) {
          int eoff = g + el;
          int de = __shfl(d_l, eoff, 64);
          float s = ssn + sd1[(size_t)de * 8 + h];
          float e = __expf(-fmaxf(s, ALPHA * s));
          if (eoff >= m) e = 0.f;
          rs += e;
          int gm = min(16, m - g);
          uint2 rv[16];
#pragma unroll
          for (int t = 0; t < 16; ++t) {
            if (t < gm) {
              int dg = __builtin_amdgcn_readlane(d_l, g + t);
              rv[t] = *(const uint2*)(tb + (size_t)dg * 1024 + L * 8);
            }
          }
#pragma unroll
          for (int t = 0; t < 16; ++t) {
            if (t < gm) {
              float ew = __shfl(e, (hq << 4) + t, 64);
              acc[0] += ew * __uint_as_float(rv[t].x << 16);
              acc[1] += ew * __uint_as_float(rv[t].x & 0xffff0000u);
              acc[2] += ew * __uint_as_float(rv[t].y << 16);
              acc[3] += ew * __uint_as_float(rv[t].y & 0xffff0000u);
            }
          }
        }
      }
      rs += __shfl_xor(rs, 1, 64);
      rs += __shfl_xor(rs, 2, 64);
      rs += __shfl_xor(rs, 4, 64);
      rs += __shfl_xor(rs, 8, 64);
      float inv = 1.f / rs;
      ushort4 pk;
      pk.x = f2bf(elu_f(acc[0] * inv));
      pk.y = f2bf(elu_f(acc[1] * inv));
      pk.z = f2bf(elu_f(acc[2] * inv));
      pk.w = f2bf(elu_f(acc[3] * inv));
      *(ushort4*)(xc + (size_t)n * 512 + p * 256 + L * 4) = pk;
    }
  }
  __threadfence();
  grid.sync();

  // ---------------- S5: layer-2 GEMM (128x64 tiles, BK=32) ----------------
  {
    typedef unsigned short (*Arr40)[40];
    Arr40 As = (Arr40)smem;
    Arr40 Bs2 = (Arr40)(smem + 10240);
    const int ntiles = NPAD / 128;  // 391
    const int w = tid >> 6, L = tid & 63;
    const int quad = L >> 4, l16 = L & 15;

    float as[4], ad[4];
#pragma unroll
    for (int nt = 0; nt < 4; ++nt) {
      as[nt] = ao[l16 + 16 * nt];
      ad[nt] = ao[64 + l16 + 16 * nt];
    }

    for (int tile = blockIdx.x; tile < ntiles; tile += gsz) {
      int m0 = tile * 128;
      f32x4 acc[2][4];
#pragma unroll
      for (int mt = 0; mt < 2; ++mt)
#pragma unroll
        for (int nt = 0; nt < 4; ++nt) acc[mt][nt] = (f32x4)(0.f);

      for (int k0 = 0; k0 < 512; k0 += 32) {
        __syncthreads();
        {
          int idx = tid;
          int r0 = idx >> 2, kq = (idx & 3) << 3;
          *(uint4*)&As[r0][kq] = *(const uint4*)(xc + (size_t)(m0 + r0) * 512 + k0 + kq);
          idx = tid + 256; r0 = idx >> 2; kq = (idx & 3) << 3;
          *(uint4*)&As[r0][kq] = *(const uint4*)(xc + (size_t)(m0 + r0) * 512 + k0 + kq);
          int n2 = tid >> 2, kq2 = (tid & 3) << 3;
          *(uint4*)&Bs2[n2][kq2] = *(const uint4*)(Wot + (size_t)n2 * 512 + k0 + kq2);
        }
        __syncthreads();

        short8 af[2], bf[4];
        af[0] = *(const short8*)&As[w * 32 + l16][quad * 8];
        af[1] = *(const short8*)&As[w * 32 + 16 + l16][quad * 8];
#pragma unroll
        for (int nt = 0; nt < 4; ++nt)
          bf[nt] = *(const short8*)&Bs2[nt * 16 + l16][quad * 8];
#pragma unroll
        for (int mt = 0; mt < 2; ++mt)
#pragma unroll
          for (int nt = 0; nt < 4; ++nt)
            acc[mt][nt] = __builtin_amdgcn_mfma_f32_16x16x32_bf16(af[mt], bf[nt], acc[mt][nt], 0, 0, 0);
      }

#pragma unroll
      for (int mt = 0; mt < 2; ++mt) {
#pragma unroll
        for (int reg = 0; reg < 4; ++reg) {
          int row = m0 + w * 32 + mt * 16 + quad * 4 + reg;
          float p = 0.f, q = 0.f;
#pragma unroll
          for (int nt = 0; nt < 4; ++nt) {
            p += acc[mt][nt][reg] * as[nt];
            q += acc[mt][nt][reg] * ad[nt];
          }
#pragma unroll
          for (int off = 1; off < 16; off <<= 1) {
            p += __shfl_xor(p, off, 64);
            q += __shfl_xor(q, off, 64);
          }
          if (l16 == 0 && row < NN) { ss2[row] = p; sd2[row] = q; }
          if (row < NN) {
#pragma unroll
            for (int nt = 0; nt < 4; ++nt)
              h2b[(size_t)row * 64 + l16 + 16 * nt] = f2bf(acc[mt][nt][reg]);
          }
        }
      }
    }
  }
  __threadfence();
  grid.sync();

  // ---------------- S6: layer-2 aggregation + classifier ----------------
  {
    float* wsh = (float*)smem;                 // 40*65
    float* bsh = wsh + 40 * 65;                // 40
    float (*osh)[68] = (float(*)[68])(bsh + 40);
    for (int i = tid; i < 40 * 64; i += 256) wsh[(i >> 6) * 65 + (i & 63)] = mw[i];
    if (tid < 40) bsh[tid] = mb[tid];
    __syncthreads();

    const int nbb = (NN + 3) / 4;
    const int wid = tid >> 6, L = tid & 63;
    for (int vb = blockIdx.x; vb < nbb; vb += gsz) {
      int n = vb * 4 + wid;
      bool act = (n < NN);
      float o = 0.f;
      if (act) {
        float ssn = ss2[n];
        int k0 = row_ptr[n], deg = row_ptr[n + 1] - k0;
        float acc = 0.f, rs = 0.f;
        const char* base = (const char*)h2b;
        for (int c0 = 0; c0 < deg; c0 += 64) {
          int j = c0 + L;
          int d_l = 0;
          float e_l = 0.f;
          if (j < deg) {
            d_l = colv[k0 + j];
            float s = ssn + sd2[d_l];
            e_l = __expf(-fmaxf(s, ALPHA * s));
          }
          rs += e_l;
          int m = min(64, deg - c0);
          int off_l = d_l << 7;
          for (int g = 0; g < m; g += 16) {
            int gm = min(16, m - g);
            unsigned hv[16];
#pragma unroll
            for (int t = 0; t < 16; ++t) {
              if (t < gm) {
                int so = __builtin_amdgcn_readlane(off_l, g + t);
                hv[t] = *(const unsigned short*)(base + so + L * 2);
              }
            }
#pragma unroll
            for (int t = 0; t < 16; ++t) {
              if (t < gm) {
                float ew = __uint_as_float(
                    (unsigned)__builtin_amdgcn_readlane(__float_as_uint(e_l), g + t));
                acc += ew * __uint_as_float(hv[t] << 16);
              }
            }
          }
        }
#pragma unroll
        for (int off = 1; off < 64; off <<= 1) rs += __shfl_xor(rs, off, 64);
        o = elu_f(acc / rs);
      }
      osh[wid][L] = o;
      __syncthreads();
      if (act && L < 40) {
        const float* wr = wsh + L * 65;
        const float* orow = osh[wid];
        float acc = bsh[L];
#pragma unroll
        for (int j = 0; j < 64; ++j) acc += orow[j] * wr[j];
        out[(size_t)n * 40 + L] = acc;
      }
      __syncthreads();
    }
  }
}

extern "C" void kernel_launch(void* const* d_in, const int* in_sizes, int n_in,
                              void* d_out, int out_size, void* d_ws, size_t ws_size,
                              hipStream_t stream) {
  (void)n_in; (void)out_size; (void)ws_size;
  const float* x  = (const float*)d_in[0];
  const int*   ei = (const int*)d_in[1];
  const float* W  = (const float*)d_in[2];
  const float* a  = (const float*)d_in[3];
  const float* Wo = (const float*)d_in[4];
  const float* ao = (const float*)d_in[5];
  const float* mw = (const float*)d_in[6];
  const float* mb = (const float*)d_in[7];
  float* out = (float*)d_out;

  const int N = NN;
  int E = in_sizes[1] / 2;
  const int* src = ei;
  const int* dst = ei + E;

  char* ws = (char*)d_ws;
  size_t off = 0;
  auto alloc = [&](size_t bytes) {
    char* p = ws + off;
    off = (off + bytes + 255) & ~(size_t)255;
    return p;
  };
  unsigned short* xb  = (unsigned short*)alloc((size_t)NPAD * 256 * 2);
  unsigned short* Wtc = (unsigned short*)alloc((size_t)512 * 256 * 2);
  unsigned short* Wot = (unsigned short*)alloc((size_t)64 * 512 * 2);
  unsigned short* h1b = (unsigned short*)alloc((size_t)N * 512 * 2);
  float* ss1     = (float*)alloc((size_t)N * 8 * 4);
  float* sd1     = (float*)alloc((size_t)N * 8 * 4);
  unsigned short* xc = (unsigned short*)alloc((size_t)NPAD * 512 * 2);
  unsigned short* h2b = (unsigned short*)alloc((size_t)N * 64 * 2);
  float* ss2     = (float*)alloc((size_t)N * 4);
  float* sd2     = (float*)alloc((size_t)N * 4);
  int*   row_ptr = (int*)  alloc((size_t)(N + 1) * 4);
  int*   nxt     = (int*)  alloc((size_t)N * 4);
  int*   cnt     = (int*)  alloc((size_t)N * 4);
  int*   colv    = (int*)  alloc((size_t)E * 4);

  int maxb = 0;
  hipOccupancyMaxActiveBlocksPerMultiprocessor(&maxb, mega_kernel, 256, 0);
  if (maxb < 1) maxb = 1;
  if (maxb > 8) maxb = 8;
  int gridsz = maxb * 256;   // 256 CUs

  void* args[] = {
    (void*)&x, (void*)&src, (void*)&dst, (void*)&W, (void*)&a, (void*)&Wo,
    (void*)&ao, (void*)&mw, (void*)&mb, (void*)&out,
    (void*)&xb, (void*)&Wtc, (void*)&Wot, (void*)&h1b, (void*)&ss1, (void*)&sd1,
    (void*)&xc, (void*)&h2b, (void*)&ss2, (void*)&sd2,
    (void*)&row_ptr, (void*)&nxt, (void*)&cnt, (void*)&colv, (void*)&E
  };
  hipLaunchCooperativeKernel(mega_kernel, dim3(gridsz), dim3(256), args, 0, stream);
}